// Round 12
// baseline (5728.146 us; speedup 1.0000x reference)
//
#include <hip/hip_runtime.h>
#include <math.h>

// Forbid fma contraction for every expression in this file (np-matching arithmetic).
#pragma clang fp contract(off)

#define NB 8
#define NP 8192
#define NS 2048
#define NK 32

// Decision-critical f32 ops as raw VALU instructions — cannot be contracted.
__device__ __forceinline__ float fsub(float a, float b) {
  float r; asm("v_sub_f32 %0, %1, %2" : "=v"(r) : "v"(a), "v"(b)); return r;
}
__device__ __forceinline__ float fmul(float a, float b) {
  float r; asm("v_mul_f32 %0, %1, %2" : "=v"(r) : "v"(a), "v"(b)); return r;
}
__device__ __forceinline__ float fadd(float a, float b) {
  float r; asm("v_add_f32 %0, %1, %2" : "=v"(r) : "v"(a), "v"(b)); return r;
}

// ---------------- FPS (passing, near VALU-bound — unchanged from R11) ----------------
__global__ __launch_bounds__(512, 1) void fps_kernel(const float* __restrict__ xyz,
                                                     float* __restrict__ new_xyz) {
  __shared__ float candx[512], candy[512], candz[512];
  __shared__ unsigned long long wbest[8];
  __shared__ float bcast[3];
  const int b = blockIdx.x;
  const int tid = threadIdx.x;
  const int lane = tid & 63, wv = tid >> 6;
  const float* xb = xyz + (size_t)b * NP * 3;
  float px[16], py[16], pz[16], dist[16];
#pragma unroll
  for (int j = 0; j < 16; j++) {
    int p = j * 512 + tid;
    px[j] = xb[p * 3 + 0]; py[j] = xb[p * 3 + 1]; pz[j] = xb[p * 3 + 2];
    dist[j] = 1e10f;
  }
  float fx = xb[0], fy = xb[1], fz = xb[2];
  for (int t = 0; t < NS; t++) {
    if (tid == 0) {
      float* o = new_xyz + ((size_t)b * NS + t) * 3;
      o[0] = fx; o[1] = fy; o[2] = fz;
    }
    float lmax = -1.0f; int larg = 0; float lx = fx, ly = fy, lz = fz;
#pragma unroll
    for (int j = 0; j < 16; j++) {
      float dx = fsub(px[j], fx);
      float dy = fsub(py[j], fy);
      float dz = fsub(pz[j], fz);
      float d = fadd(fadd(fmul(dx, dx), fmul(dy, dy)), fmul(dz, dz));
      float nd = fminf(dist[j], d);
      dist[j] = nd;
      if (nd > lmax) { lmax = nd; larg = j * 512 + tid; lx = px[j]; ly = py[j]; lz = pz[j]; }
    }
    candx[tid] = lx; candy[tid] = ly; candz[tid] = lz;
    unsigned long long m = ((unsigned long long)__float_as_uint(lmax) << 32)
                         | (unsigned long long)(unsigned)(~(unsigned)larg);
#pragma unroll
    for (int off = 32; off > 0; off >>= 1) {
      unsigned long long o2 = __shfl_down(m, off);
      if (o2 > m) m = o2;
    }
    if (lane == 0) wbest[wv] = m;
    __syncthreads();
    if (tid == 0) {
      unsigned long long mm = wbest[0];
#pragma unroll
      for (int w = 1; w < 8; w++) if (wbest[w] > mm) mm = wbest[w];
      unsigned widx = ~(unsigned)(mm & 0xFFFFFFFFull);
      int owner = (int)(widx & 511u);
      bcast[0] = candx[owner]; bcast[1] = candy[owner]; bcast[2] = candz[owner];
    }
    __syncthreads();
    fx = bcast[0]; fy = bcast[1]; fz = bcast[2];
  }
}

// ---------------- Fused ball query + gather + MLP + maxpool (restructured) ----------------
// Phase A: identical keys/selection semantics as R11, but keys held in registers,
// round-0 histogram ballot-aggregated, bucket scan parallelized (same global-rank rule).
// Phase B: weights/BN read from global (L2-hot), x1/x2 in LDS, register tiles.
__global__ __launch_bounds__(256) void ball_mlp_kernel(
    const float* __restrict__ xyz, const float* __restrict__ points,
    const float* __restrict__ new_xyz,
    const float* __restrict__ w0, const float* __restrict__ b0, const float* __restrict__ g0,
    const float* __restrict__ bt0, const float* __restrict__ m0, const float* __restrict__ v0,
    const float* __restrict__ w1, const float* __restrict__ b1, const float* __restrict__ g1,
    const float* __restrict__ bt1, const float* __restrict__ m1, const float* __restrict__ v1,
    const float* __restrict__ w2, const float* __restrict__ b2, const float* __restrict__ g2,
    const float* __restrict__ bt2, const float* __restrict__ m2, const float* __restrict__ v2,
    float* __restrict__ out_pts) {
  __shared__ __align__(16) float smem[9552];     // 38208 B -> 4 blocks/CU
  // ---- phase A ----
  float* sd         = smem;                      // 8192 keys (written once, read at end)
  int* hist         = (int*)(smem + 8192);       // 256
  int* cnts         = (int*)(smem + 8448);       // 2
  unsigned* sprefix = (unsigned*)(smem + 8450);
  int* sbelow       = (int*)(smem + 8451);
  int* snear_s      = (int*)(smem + 8452);
  int* selA         = (int*)(smem + 8456);       // 32
  int* tib          = (int*)(smem + 8488);       // 1024
  int* qsel         = (int*)(smem + 9512);       // 32 (survives into phase B)
  int* wsum         = (int*)(smem + 9544);       // 4 scan partials
  // ---- phase B (overlays sd region) ----
  float* x1   = smem;             // 32*64
  float* x2   = smem + 2048;      // 32*64
  float* pmax = smem + 4096;      // 16*128
  float* gin  = smem + 6144;      // 32*12 (stride 12, b128-readable)

  const int cs = blockIdx.x;
  const int b = cs >> 11;
  const int tid = threadIdx.x;
  const int lane = tid & 63, wv = tid >> 6;
  const float* xb = xyz + (size_t)b * NP * 3;
  const float cx = new_xyz[cs * 3 + 0], cy = new_xyz[cs * 3 + 1], cz = new_xyz[cs * 3 + 2];
  const float Sc = fadd(fadd(fmul(cx, cx), fmul(cy, cy)), fmul(cz, cz));
  float key[32];
#pragma unroll
  for (int j = 0; j < 32; j++) {
    int p = j * 256 + tid;
    float x = xb[p * 3 + 0], y = xb[p * 3 + 1], z = xb[p * 3 + 2];
    float Sn    = fadd(fadd(fmul(x, x), fmul(y, y)), fmul(z, z));
    float inner = fmaf(cz, z, fmaf(cy, y, fmul(cx, x)));
    float d2    = fsub(fadd(Sc, Sn), fmul(2.0f, inner));
    float kk = __fsqrt_rn(fmaxf(d2, 0.0f));
    key[j] = kk;
    sd[p] = kk;
  }
  // 4-round radix select of the 32nd-smallest key (global-rank crossing rule)
  unsigned prefix = 0; int below = 0;
  for (int round = 0; round < 4; round++) {
    const int shift = 24 - 8 * round;
    hist[tid] = 0;
    __syncthreads();
    if (round == 0) {
      // ballot-aggregated: one atomic per (wave, distinct bucket)
#pragma unroll
      for (int j = 0; j < 32; j++) {
        unsigned bucket = __float_as_uint(key[j]) >> 24;
        unsigned long long mask = ~0ull;
#pragma unroll
        for (int bit = 0; bit < 8; bit++) {
          unsigned long long bb = __ballot((bucket >> bit) & 1u);
          mask &= ((bucket >> bit) & 1u) ? bb : ~bb;
        }
        int leader = __ffsll((unsigned long long)mask) - 1;
        if (lane == leader) atomicAdd(&hist[bucket], (int)__popcll(mask));
      }
    } else {
#pragma unroll
      for (int j = 0; j < 32; j++) {
        unsigned kb = __float_as_uint(key[j]);
        if ((kb >> (shift + 8)) == (prefix >> (shift + 8)))
          atomicAdd(&hist[(kb >> shift) & 255], 1);
      }
    }
    __syncthreads();
    // parallel prefix over 256 buckets; unique thread where excl < NK <= excl+h
    int h = hist[tid];
    int v = h;
#pragma unroll
    for (int off = 1; off < 64; off <<= 1) {
      int u = __shfl_up(v, off);
      if (lane >= off) v += u;
    }
    if (lane == 63) wsum[wv] = v;
    __syncthreads();
    int base = below;
    for (int w = 0; w < wv; w++) base += wsum[w];
    int excl = base + v - h;
    if (excl < NK && excl + h >= NK) {
      *sprefix = prefix | ((unsigned)tid << shift);
      *sbelow = excl;
    }
    __syncthreads();
    prefix = *sprefix; below = *sbelow;
  }
  const unsigned K32 = prefix;
  if (tid < 2) cnts[tid] = 0;
  __syncthreads();
#pragma unroll
  for (int j = 0; j < 32; j++) {
    int p = j * 256 + tid;
    unsigned kb = __float_as_uint(key[j]);
    if (kb < K32) { int q = atomicAdd(&cnts[0], 1); if (q < NK) selA[q] = p; }
    else if (kb == K32) { int q = atomicAdd(&cnts[1], 1); if (q < 1024) tib[q] = p; }
  }
  __syncthreads();
  const int n1 = cnts[0] < NK ? cnts[0] : NK;
  int nt = cnts[1]; if (nt > 1024) nt = 1024;
  if (tid == 0) {
    int need = NK - n1;
    for (int a = 0; a < need; a++) {       // ties -> lowest indices (top_k stable)
      int bj = -1; int bidx = 0x7fffffff;
      for (int j = 0; j < nt; j++) {
        int p = tib[j];
        if (p >= 0 && p < bidx) { bidx = p; bj = j; }
      }
      if (bj >= 0) { selA[n1 + a] = bidx; tib[bj] = -1; }
      else selA[n1 + a] = selA[0];
    }
    float bk = 1e30f; int bp = 0x7fffffff;  // nearest = (min key, min idx)
    for (int j = 0; j < NK; j++) {
      int p = selA[j]; float kk = sd[p];
      if (kk < bk || (kk == bk && p < bp)) { bk = kk; bp = p; }
    }
    *snear_s = bp;
  }
  __syncthreads();
  if (tid < NK) {
    int p = selA[tid];
    qsel[tid] = (sd[p] > 0.25f) ? *snear_s : p;
  }
  __syncthreads();

  // ---- phase B ----
  for (int e = tid; e < 288; e += 256) {
    int k = e / 9, c = e % 9;
    int p = qsel[k];
    float v;
    if (c < 3) {
      float cc = (c == 0) ? cx : (c == 1 ? cy : cz);
      v = fsub(xyz[((size_t)b * NP + p) * 3 + c], cc);
    } else {
      v = points[((size_t)b * NP + p) * 6 + (c - 3)];
    }
    gin[k * 12 + c] = v;
  }
  __syncthreads();
  { // L1: 1 o x 8 k per thread; w0/bn from global
    int o = tid & 63, k0 = (tid >> 6) * 8;
    float wr[9];
#pragma unroll
    for (int c = 0; c < 9; c++) wr[c] = w0[o * 9 + c];
    float bb = b0[o], bm = m0[o], bg = g0[o], bbt = bt0[o];
    float br = 1.0f / __fsqrt_rn(fadd(v0[o], 1e-5f));
#pragma unroll
    for (int j = 0; j < 8; j++) {
      int k = k0 + j;
      const float4* gq = (const float4*)&gin[k * 12];
      float4 q0 = gq[0], q1 = gq[1], q2 = gq[2];
      float acc = 0.f;
      acc = fmaf(wr[0], q0.x, acc); acc = fmaf(wr[1], q0.y, acc);
      acc = fmaf(wr[2], q0.z, acc); acc = fmaf(wr[3], q0.w, acc);
      acc = fmaf(wr[4], q1.x, acc); acc = fmaf(wr[5], q1.y, acc);
      acc = fmaf(wr[6], q1.z, acc); acc = fmaf(wr[7], q1.w, acc);
      acc = fmaf(wr[8], q2.x, acc);
      float y = fadd(acc, bb);
      y = fadd(fmul(fmul(bg, fsub(y, bm)), br), bbt);
      x1[k * 64 + o] = fmaxf(y, 0.f);
    }
  }
  __syncthreads();
  { // L2: 4 o x 2 k per thread; w1/bn from global, x1 from LDS
    int o0 = (tid & 15) * 4, k0 = (tid >> 4) * 2;
    float acc[4][2];
#pragma unroll
    for (int oo = 0; oo < 4; oo++) { acc[oo][0] = 0.f; acc[oo][1] = 0.f; }
#pragma unroll
    for (int c4 = 0; c4 < 16; c4++) {
      float4 xq0 = *(const float4*)&x1[k0 * 64 + c4 * 4];
      float4 xq1 = *(const float4*)&x1[(k0 + 1) * 64 + c4 * 4];
#pragma unroll
      for (int oo = 0; oo < 4; oo++) {
        float4 wq = *(const float4*)&w1[(o0 + oo) * 64 + c4 * 4];
        acc[oo][0] = fmaf(wq.x, xq0.x, acc[oo][0]);
        acc[oo][0] = fmaf(wq.y, xq0.y, acc[oo][0]);
        acc[oo][0] = fmaf(wq.z, xq0.z, acc[oo][0]);
        acc[oo][0] = fmaf(wq.w, xq0.w, acc[oo][0]);
        acc[oo][1] = fmaf(wq.x, xq1.x, acc[oo][1]);
        acc[oo][1] = fmaf(wq.y, xq1.y, acc[oo][1]);
        acc[oo][1] = fmaf(wq.z, xq1.z, acc[oo][1]);
        acc[oo][1] = fmaf(wq.w, xq1.w, acc[oo][1]);
      }
    }
#pragma unroll
    for (int oo = 0; oo < 4; oo++) {
      int o = o0 + oo;
      float bb = b1[o], bm = m1[o], bg = g1[o], bbt = bt1[o];
      float br = 1.0f / __fsqrt_rn(fadd(v1[o], 1e-5f));
#pragma unroll
      for (int kk = 0; kk < 2; kk++) {
        float y = fadd(acc[oo][kk], bb);
        y = fadd(fmul(fmul(bg, fsub(y, bm)), br), bbt);
        x2[(k0 + kk) * 64 + o] = fmaxf(y, 0.f);
      }
    }
  }
  __syncthreads();
  { // L3: 8 ch x 2 k per thread; w2/bn from global, x2 from LDS
    int ch0 = (tid & 15) * 8, k0 = (tid >> 4) * 2, kg = tid >> 4;
    float acc[8][2];
#pragma unroll
    for (int cc = 0; cc < 8; cc++) { acc[cc][0] = 0.f; acc[cc][1] = 0.f; }
#pragma unroll
    for (int c4 = 0; c4 < 16; c4++) {
      float4 xq0 = *(const float4*)&x2[k0 * 64 + c4 * 4];
      float4 xq1 = *(const float4*)&x2[(k0 + 1) * 64 + c4 * 4];
#pragma unroll
      for (int cc = 0; cc < 8; cc++) {
        float4 wq = *(const float4*)&w2[(ch0 + cc) * 64 + c4 * 4];
        acc[cc][0] = fmaf(wq.x, xq0.x, acc[cc][0]);
        acc[cc][0] = fmaf(wq.y, xq0.y, acc[cc][0]);
        acc[cc][0] = fmaf(wq.z, xq0.z, acc[cc][0]);
        acc[cc][0] = fmaf(wq.w, xq0.w, acc[cc][0]);
        acc[cc][1] = fmaf(wq.x, xq1.x, acc[cc][1]);
        acc[cc][1] = fmaf(wq.y, xq1.y, acc[cc][1]);
        acc[cc][1] = fmaf(wq.z, xq1.z, acc[cc][1]);
        acc[cc][1] = fmaf(wq.w, xq1.w, acc[cc][1]);
      }
    }
#pragma unroll
    for (int cc = 0; cc < 8; cc++) {
      int ch = ch0 + cc;
      float bb = b2[ch], bm = m2[ch], bg = g2[ch], bbt = bt2[ch];
      float br = 1.0f / __fsqrt_rn(fadd(v2[ch], 1e-5f));
      float y0 = fadd(acc[cc][0], bb);
      y0 = fadd(fmul(fmul(bg, fsub(y0, bm)), br), bbt);
      float y1 = fadd(acc[cc][1], bb);
      y1 = fadd(fmul(fmul(bg, fsub(y1, bm)), br), bbt);
      pmax[kg * 128 + ch] = fmaxf(fmaxf(y0, 0.f), fmaxf(y1, 0.f));
    }
  }
  __syncthreads();
  if (tid < 128) {
    float m = pmax[tid];
#pragma unroll
    for (int g = 1; g < 16; g++) m = fmaxf(m, pmax[g * 128 + tid]);
    out_pts[(size_t)cs * 128 + tid] = m;
  }
}

extern "C" void kernel_launch(void* const* d_in, const int* in_sizes, int n_in,
                              void* d_out, int out_size, void* d_ws, size_t ws_size,
                              hipStream_t stream) {
  (void)in_sizes; (void)n_in; (void)out_size; (void)d_ws; (void)ws_size;
  const float* xyz    = (const float*)d_in[0];
  const float* points = (const float*)d_in[1];
  const float* w0 = (const float*)d_in[2];
  const float* b0 = (const float*)d_in[3];
  const float* g0 = (const float*)d_in[4];
  const float* bt0 = (const float*)d_in[5];
  const float* m0 = (const float*)d_in[6];
  const float* v0 = (const float*)d_in[7];
  const float* w1 = (const float*)d_in[8];
  const float* b1 = (const float*)d_in[9];
  const float* g1 = (const float*)d_in[10];
  const float* bt1 = (const float*)d_in[11];
  const float* m1 = (const float*)d_in[12];
  const float* v1 = (const float*)d_in[13];
  const float* w2 = (const float*)d_in[14];
  const float* b2 = (const float*)d_in[15];
  const float* g2 = (const float*)d_in[16];
  const float* bt2 = (const float*)d_in[17];
  const float* m2 = (const float*)d_in[18];
  const float* v2 = (const float*)d_in[19];

  float* new_xyz = (float*)d_out;                         // 8*2048*3 f32
  float* out_pts = (float*)d_out + (size_t)NB * NS * 3;   // 8*2048*128 f32

  fps_kernel<<<NB, 512, 0, stream>>>(xyz, new_xyz);
  ball_mlp_kernel<<<NB * NS, 256, 0, stream>>>(xyz, points, new_xyz,
                                               w0, b0, g0, bt0, m0, v0,
                                               w1, b1, g1, bt1, m1, v1,
                                               w2, b2, g2, bt2, m2, v2,
                                               out_pts);
}

// Round 13
// 4559.368 us; speedup vs baseline: 1.2563x; 1.2563x over previous
//
#include <hip/hip_runtime.h>
#include <math.h>

// Forbid fma contraction for every expression in this file (np-matching arithmetic).
#pragma clang fp contract(off)

#define NB 8
#define NP 8192
#define NS 2048
#define NK 32

// Decision-critical f32 ops as raw VALU instructions — cannot be contracted.
__device__ __forceinline__ float fsub(float a, float b) {
  float r; asm("v_sub_f32 %0, %1, %2" : "=v"(r) : "v"(a), "v"(b)); return r;
}
__device__ __forceinline__ float fmul(float a, float b) {
  float r; asm("v_mul_f32 %0, %1, %2" : "=v"(r) : "v"(a), "v"(b)); return r;
}
__device__ __forceinline__ float fadd(float a, float b) {
  float r; asm("v_add_f32 %0, %1, %2" : "=v"(r) : "v"(a), "v"(b)); return r;
}

// ---------------- FPS: 1024 threads x 8 pts, ONE barrier/iter ----------------
// Exact semantics of the passing kernel: unfused f32 distances, u64 (key<<32|~idx)
// max == (max key, lowest index) == np.argmax. Parity double-buffer removes the
// write-after-read race; every thread redundantly reduces the 16 wave bests.
__global__ __launch_bounds__(1024, 1) void fps_kernel(const float* __restrict__ xyz,
                                                      float* __restrict__ new_xyz) {
  __shared__ float candx[2][1024], candy[2][1024], candz[2][1024];
  __shared__ unsigned long long wbest[2][16];
  const int b = blockIdx.x;
  const int tid = threadIdx.x;
  const int lane = tid & 63, wv = tid >> 6;
  const float* xb = xyz + (size_t)b * NP * 3;
  float px[8], py[8], pz[8], dist[8];
#pragma unroll
  for (int j = 0; j < 8; j++) {
    int p = j * 1024 + tid;
    px[j] = xb[p * 3 + 0]; py[j] = xb[p * 3 + 1]; pz[j] = xb[p * 3 + 2];
    dist[j] = 1e10f;
  }
  float fx = xb[0], fy = xb[1], fz = xb[2];   // farthest = index 0 at t=0
  for (int t = 0; t < NS; t++) {
    if (tid == 0) {
      float* o = new_xyz + ((size_t)b * NS + t) * 3;
      o[0] = fx; o[1] = fy; o[2] = fz;
    }
    const int par = t & 1;
    float lmax = -1.0f; int larg = 0; float lx = fx, ly = fy, lz = fz;
#pragma unroll
    for (int j = 0; j < 8; j++) {
      float dx = fsub(px[j], fx);
      float dy = fsub(py[j], fy);
      float dz = fsub(pz[j], fz);
      float d = fadd(fadd(fmul(dx, dx), fmul(dy, dy)), fmul(dz, dz));
      float nd = fminf(dist[j], d);
      dist[j] = nd;
      // ascending j => ascending global idx: strict '>' keeps lowest idx
      if (nd > lmax) { lmax = nd; larg = j * 1024 + tid; lx = px[j]; ly = py[j]; lz = pz[j]; }
    }
    candx[par][tid] = lx; candy[par][tid] = ly; candz[par][tid] = lz;
    unsigned long long m = ((unsigned long long)__float_as_uint(lmax) << 32)
                         | (unsigned long long)(unsigned)(~(unsigned)larg);
#pragma unroll
    for (int off = 32; off > 0; off >>= 1) {
      unsigned long long o2 = __shfl_down(m, off);
      if (o2 > m) m = o2;
    }
    if (lane == 0) wbest[par][wv] = m;
    __syncthreads();                    // single barrier per iteration
    unsigned long long mm = wbest[par][0];
#pragma unroll
    for (int w = 1; w < 16; w++) { unsigned long long c = wbest[par][w]; if (c > mm) mm = c; }
    int owner = (int)((~(unsigned)(mm & 0xFFFFFFFFull)) & 1023u);   // idx = j*1024+tid
    fx = candx[par][owner]; fy = candy[par][owner]; fz = candz[par][owner];
    // parity buffer: next iteration writes [1-par] — no race with this read
  }
}

// ---------------- Fused ball query + gather + MLP + maxpool ----------------
// Selection semantics identical to R11/R12 (passing): same keys, radix rounds,
// global-rank crossing rule, lowest-index ties, radius on sqrt key.
__global__ __launch_bounds__(256, 4) void ball_mlp_kernel(
    const float* __restrict__ xyz, const float* __restrict__ points,
    const float* __restrict__ new_xyz,
    const float* __restrict__ w0, const float* __restrict__ b0, const float* __restrict__ g0,
    const float* __restrict__ bt0, const float* __restrict__ m0, const float* __restrict__ v0,
    const float* __restrict__ w1, const float* __restrict__ b1, const float* __restrict__ g1,
    const float* __restrict__ bt1, const float* __restrict__ m1, const float* __restrict__ v1,
    const float* __restrict__ w2, const float* __restrict__ b2, const float* __restrict__ g2,
    const float* __restrict__ bt2, const float* __restrict__ m2, const float* __restrict__ v2,
    float* __restrict__ out_pts) {
  __shared__ __align__(16) float smem[9552];     // 38208 B -> 4 blocks/CU (LDS)
  // ---- phase A ----
  float* sd         = smem;                      // 8192 keys
  int* hist4        = (int*)(smem + 8192);       // 4 waves x 256 buckets
  int* cnts         = (int*)(smem + 9216);       // 2
  unsigned* sprefix = (unsigned*)(smem + 9218);
  int* sbelow       = (int*)(smem + 9219);
  int* snear_s      = (int*)(smem + 9220);
  int* wsum         = (int*)(smem + 9224);       // 4
  int* selA         = (int*)(smem + 9232);       // 32
  int* tib          = (int*)(smem + 9264);       // 256
  int* qsel         = (int*)(smem + 9520);       // 32 (survives into phase B)
  // ---- phase B (overlays sd) ----
  float* x1   = smem;             // 32*64
  float* x2   = smem + 2048;      // 32*64
  float* pmax = smem + 4096;      // 8*128
  float* gin  = smem + 5120;      // 32*12

  const int cs = blockIdx.x;
  const int b = cs >> 11;
  const int tid = threadIdx.x;
  const int lane = tid & 63, wv = tid >> 6;
  int* myhist = hist4 + wv * 256;
  const float* xb = xyz + (size_t)b * NP * 3;
  const float cx = new_xyz[cs * 3 + 0], cy = new_xyz[cs * 3 + 1], cz = new_xyz[cs * 3 + 2];
  const float Sc = fadd(fadd(fmul(cx, cx), fmul(cy, cy)), fmul(cz, cz));
  // zero own wave's histogram (wave-local, no barrier needed before atomics)
  for (int i = lane; i < 256; i += 64) myhist[i] = 0;
  // keys + round-0 histogram fused
  for (int j = 0; j < 32; j++) {
    int p = j * 256 + tid;
    float x = xb[p * 3 + 0], y = xb[p * 3 + 1], z = xb[p * 3 + 2];
    float Sn    = fadd(fadd(fmul(x, x), fmul(y, y)), fmul(z, z));
    float inner = fmaf(cz, z, fmaf(cy, y, fmul(cx, x)));
    float d2    = fsub(fadd(Sc, Sn), fmul(2.0f, inner));
    float kk = __fsqrt_rn(fmaxf(d2, 0.0f));
    sd[p] = kk;
    atomicAdd(&myhist[__float_as_uint(kk) >> 24], 1);
  }
  // 4-round radix select (round 0 histogram already done)
  unsigned prefix = 0; int below = 0;
  for (int round = 0; round < 4; round++) {
    const int shift = 24 - 8 * round;
    if (round > 0) {
      for (int i = lane; i < 256; i += 64) myhist[i] = 0;
      __syncthreads();    // hist4 of prev round fully read before re-zero? (zero own copy
                          // only touches own wave's; but scan read ALL copies) — barrier above
      for (int j = 0; j < 32; j++) {
        unsigned kb = __float_as_uint(sd[j * 256 + tid]);
        if ((kb >> (shift + 8)) == (prefix >> (shift + 8)))
          atomicAdd(&myhist[(kb >> shift) & 255], 1);
      }
    }
    __syncthreads();
    int h = hist4[tid] + hist4[256 + tid] + hist4[512 + tid] + hist4[768 + tid];
    int v = h;
#pragma unroll
    for (int off = 1; off < 64; off <<= 1) {
      int u = __shfl_up(v, off);
      if (lane >= off) v += u;
    }
    if (lane == 63) wsum[wv] = v;
    __syncthreads();
    int base = below;
    for (int w = 0; w < wv; w++) base += wsum[w];
    int excl = base + v - h;
    if (excl < NK && excl + h >= NK) {    // unique crossing thread
      *sprefix = prefix | ((unsigned)tid << shift);
      *sbelow = excl;
    }
    __syncthreads();
    prefix = *sprefix; below = *sbelow;
  }
  const unsigned K32 = prefix;
  if (tid < 2) cnts[tid] = 0;
  __syncthreads();
  for (int j = 0; j < 32; j++) {
    int p = j * 256 + tid;
    unsigned kb = __float_as_uint(sd[p]);
    if (kb < K32) { int q = atomicAdd(&cnts[0], 1); if (q < NK) selA[q] = p; }
    else if (kb == K32) { int q = atomicAdd(&cnts[1], 1); if (q < 256) tib[q] = p; }
  }
  __syncthreads();
  const int n1 = cnts[0] < NK ? cnts[0] : NK;
  int nt = cnts[1]; if (nt > 256) nt = 256;
  if (tid == 0) {
    int need = NK - n1;
    for (int a = 0; a < need; a++) {       // ties -> lowest indices (top_k stable)
      int bj = -1; int bidx = 0x7fffffff;
      for (int j = 0; j < nt; j++) {
        int p = tib[j];
        if (p >= 0 && p < bidx) { bidx = p; bj = j; }
      }
      if (bj >= 0) { selA[n1 + a] = bidx; tib[bj] = -1; }
      else selA[n1 + a] = selA[0];
    }
    float bk = 1e30f; int bp = 0x7fffffff;  // nearest = (min key, min idx)
    for (int j = 0; j < NK; j++) {
      int p = selA[j]; float kk = sd[p];
      if (kk < bk || (kk == bk && p < bp)) { bk = kk; bp = p; }
    }
    *snear_s = bp;
  }
  __syncthreads();
  if (tid < NK) {
    int p = selA[tid];
    qsel[tid] = (sd[p] > 0.25f) ? *snear_s : p;
  }
  __syncthreads();

  // ---- phase B (overlays sd; qsel lives above the overlay) ----
  for (int e = tid; e < 288; e += 256) {
    int k = e / 9, c = e % 9;
    int p = qsel[k];
    float v;
    if (c < 3) {
      float cc = (c == 0) ? cx : (c == 1 ? cy : cz);
      v = fsub(xyz[((size_t)b * NP + p) * 3 + c], cc);
    } else {
      v = points[((size_t)b * NP + p) * 6 + (c - 3)];
    }
    gin[k * 12 + c] = v;
  }
  __syncthreads();
  { // L1: 1 o x 8 k per thread; w0/bn from global (L2-hot)
    int o = tid & 63, k0 = (tid >> 6) * 8;
    float wr[9];
#pragma unroll
    for (int c = 0; c < 9; c++) wr[c] = w0[o * 9 + c];
    float bb = b0[o], bm = m0[o], bg = g0[o], bbt = bt0[o];
    float br = 1.0f / __fsqrt_rn(fadd(v0[o], 1e-5f));
#pragma unroll
    for (int j = 0; j < 8; j++) {
      int k = k0 + j;
      const float4* gq = (const float4*)&gin[k * 12];
      float4 q0 = gq[0], q1 = gq[1], q2 = gq[2];
      float acc = 0.f;
      acc = fmaf(wr[0], q0.x, acc); acc = fmaf(wr[1], q0.y, acc);
      acc = fmaf(wr[2], q0.z, acc); acc = fmaf(wr[3], q0.w, acc);
      acc = fmaf(wr[4], q1.x, acc); acc = fmaf(wr[5], q1.y, acc);
      acc = fmaf(wr[6], q1.z, acc); acc = fmaf(wr[7], q1.w, acc);
      acc = fmaf(wr[8], q2.x, acc);
      float y = fadd(acc, bb);
      y = fadd(fmul(fmul(bg, fsub(y, bm)), br), bbt);
      x1[k * 64 + o] = fmaxf(y, 0.f);
    }
  }
  __syncthreads();
  { // L2: 2 o x 4 k per thread
    int o0 = (tid & 31) * 2, k0 = (tid >> 5) * 4;
    float acc[2][4];
#pragma unroll
    for (int oo = 0; oo < 2; oo++)
#pragma unroll
      for (int kk = 0; kk < 4; kk++) acc[oo][kk] = 0.f;
#pragma unroll
    for (int c4 = 0; c4 < 16; c4++) {
      float4 xq[4];
#pragma unroll
      for (int kk = 0; kk < 4; kk++) xq[kk] = *(const float4*)&x1[(k0 + kk) * 64 + c4 * 4];
#pragma unroll
      for (int oo = 0; oo < 2; oo++) {
        float4 wq = *(const float4*)&w1[(o0 + oo) * 64 + c4 * 4];
#pragma unroll
        for (int kk = 0; kk < 4; kk++) {
          acc[oo][kk] = fmaf(wq.x, xq[kk].x, acc[oo][kk]);
          acc[oo][kk] = fmaf(wq.y, xq[kk].y, acc[oo][kk]);
          acc[oo][kk] = fmaf(wq.z, xq[kk].z, acc[oo][kk]);
          acc[oo][kk] = fmaf(wq.w, xq[kk].w, acc[oo][kk]);
        }
      }
    }
#pragma unroll
    for (int oo = 0; oo < 2; oo++) {
      int o = o0 + oo;
      float bb = b1[o], bm = m1[o], bg = g1[o], bbt = bt1[o];
      float br = 1.0f / __fsqrt_rn(fadd(v1[o], 1e-5f));
#pragma unroll
      for (int kk = 0; kk < 4; kk++) {
        float y = fadd(acc[oo][kk], bb);
        y = fadd(fmul(fmul(bg, fsub(y, bm)), br), bbt);
        x2[(k0 + kk) * 64 + o] = fmaxf(y, 0.f);
      }
    }
  }
  __syncthreads();
  { // L3: 4 ch x 4 k per thread + per-k-group max
    int ch0 = (tid & 31) * 4, k0 = (tid >> 5) * 4, kg = tid >> 5;
    float acc[4][4];
#pragma unroll
    for (int cc = 0; cc < 4; cc++)
#pragma unroll
      for (int kk = 0; kk < 4; kk++) acc[cc][kk] = 0.f;
#pragma unroll
    for (int c4 = 0; c4 < 16; c4++) {
      float4 xq[4];
#pragma unroll
      for (int kk = 0; kk < 4; kk++) xq[kk] = *(const float4*)&x2[(k0 + kk) * 64 + c4 * 4];
#pragma unroll
      for (int cc = 0; cc < 4; cc++) {
        float4 wq = *(const float4*)&w2[(ch0 + cc) * 64 + c4 * 4];
#pragma unroll
        for (int kk = 0; kk < 4; kk++) {
          acc[cc][kk] = fmaf(wq.x, xq[kk].x, acc[cc][kk]);
          acc[cc][kk] = fmaf(wq.y, xq[kk].y, acc[cc][kk]);
          acc[cc][kk] = fmaf(wq.z, xq[kk].z, acc[cc][kk]);
          acc[cc][kk] = fmaf(wq.w, xq[kk].w, acc[cc][kk]);
        }
      }
    }
#pragma unroll
    for (int cc = 0; cc < 4; cc++) {
      int ch = ch0 + cc;
      float bb = b2[ch], bm = m2[ch], bg = g2[ch], bbt = bt2[ch];
      float br = 1.0f / __fsqrt_rn(fadd(v2[ch], 1e-5f));
      float mx = -1e30f;
#pragma unroll
      for (int kk = 0; kk < 4; kk++) {
        float y = fadd(acc[cc][kk], bb);
        y = fadd(fmul(fmul(bg, fsub(y, bm)), br), bbt);
        mx = fmaxf(mx, fmaxf(y, 0.f));
      }
      pmax[kg * 128 + ch] = mx;
    }
  }
  __syncthreads();
  if (tid < 128) {
    float m = pmax[tid];
#pragma unroll
    for (int g = 1; g < 8; g++) m = fmaxf(m, pmax[g * 128 + tid]);
    out_pts[(size_t)cs * 128 + tid] = m;
  }
}

extern "C" void kernel_launch(void* const* d_in, const int* in_sizes, int n_in,
                              void* d_out, int out_size, void* d_ws, size_t ws_size,
                              hipStream_t stream) {
  (void)in_sizes; (void)n_in; (void)out_size; (void)d_ws; (void)ws_size;
  const float* xyz    = (const float*)d_in[0];
  const float* points = (const float*)d_in[1];
  const float* w0 = (const float*)d_in[2];
  const float* b0 = (const float*)d_in[3];
  const float* g0 = (const float*)d_in[4];
  const float* bt0 = (const float*)d_in[5];
  const float* m0 = (const float*)d_in[6];
  const float* v0 = (const float*)d_in[7];
  const float* w1 = (const float*)d_in[8];
  const float* b1 = (const float*)d_in[9];
  const float* g1 = (const float*)d_in[10];
  const float* bt1 = (const float*)d_in[11];
  const float* m1 = (const float*)d_in[12];
  const float* v1 = (const float*)d_in[13];
  const float* w2 = (const float*)d_in[14];
  const float* b2 = (const float*)d_in[15];
  const float* g2 = (const float*)d_in[16];
  const float* bt2 = (const float*)d_in[17];
  const float* m2 = (const float*)d_in[18];
  const float* v2 = (const float*)d_in[19];

  float* new_xyz = (float*)d_out;                         // 8*2048*3 f32
  float* out_pts = (float*)d_out + (size_t)NB * NS * 3;   // 8*2048*128 f32

  fps_kernel<<<NB, 1024, 0, stream>>>(xyz, new_xyz);
  ball_mlp_kernel<<<NB * NS, 256, 0, stream>>>(xyz, points, new_xyz,
                                               w0, b0, g0, bt0, m0, v0,
                                               w1, b1, g1, bt1, m1, v1,
                                               w2, b2, g2, bt2, m2, v2,
                                               out_pts);
}